// Round 9
// baseline (661.951 us; speedup 1.0000x reference)
//
#include <hip/hip_runtime.h>
#include <hip/hip_bf16.h>

// GIN 2-layer + BN + softmax pipeline for MI355X. All tensors fp32; edges int32.
// R9: all four 128x128 GEMMs moved to bf16 MFMA (16x16x32), barrier-free,
// register-resident A-fragments, bf16-transposed weights prepped once.
//
// Workspace timeline (B0/B1/B2 = 25.6 MB fp32 regions; b* = bf16 aliases):
//   to_bf16:  xb=(u16*)B2  <- x
//   gather1:  reads xb(B2)    -> H0b=(u16*)B0
//   gemm1:    A=H0b(B0)       -> mid1b=(u16*)B2 (ReLU; kills xb, OK)
//   gemm2s:   A=mid1b(B2)     -> hb=(u16*)B0 + stats1 (kills H0b, OK)
//   gather2:  reads hb(B0)+BN -> H2b=(u16*)B2 (kills mid1b, OK)
//   gemm3:    A=H2b(B2)       -> mid2b=(u16*)B0 (ReLU; kills hb, OK)
//   gemm4s:   A=mid2b(B0)     -> h2 fp32 = B1 + stats2
//   out_proj: reads B1 (+BN2 fused)

#define NNODES 50000
#define NEDGES 800000
#define HD 128
#define KOUT 64

typedef __attribute__((ext_vector_type(8))) short bf16x8;
typedef __attribute__((ext_vector_type(4))) float f32x4;

__device__ __forceinline__ unsigned short f2bf(float f) {   // RNE bf16
    unsigned u = __float_as_uint(f);
    u += 0x7fffu + ((u >> 16) & 1u);
    return (unsigned short)(u >> 16);
}
__device__ __forceinline__ float4 bf4_to_f4(ushort4 u) {
    float4 v;
    v.x = __uint_as_float((unsigned)u.x << 16);
    v.y = __uint_as_float((unsigned)u.y << 16);
    v.z = __uint_as_float((unsigned)u.z << 16);
    v.w = __uint_as_float((unsigned)u.w << 16);
    return v;
}

// ================= fp32 -> bf16 copy =================
__global__ __launch_bounds__(256) void to_bf16(
    const float* __restrict__ in, unsigned short* __restrict__ out)
{
    int i = blockIdx.x * 256 + threadIdx.x;     // float4 index
    float4 v = ((const float4*)in)[i];
    ushort4 o;
    o.x = f2bf(v.x); o.y = f2bf(v.y); o.z = f2bf(v.z); o.w = f2bf(v.w);
    ((ushort4*)out)[i] = o;
}

// ============ weight transpose to bf16: Wt[n][k] = bf16(W[k][n]) ============
__global__ __launch_bounds__(256) void transpose_bf16(
    const float* __restrict__ W, unsigned short* __restrict__ Wt)
{
    int idx = blockIdx.x * 256 + threadIdx.x;   // 0 .. 128*128
    int n = idx >> 7, k = idx & 127;
    Wt[idx] = f2bf(W[k * HD + n]);
}

// ================= CSR build =================
__global__ __launch_bounds__(256) void edge_hist(
    const int* __restrict__ ei, int* __restrict__ deg)
{
    int e = blockIdx.x * 256 + threadIdx.x;
    if (e < NEDGES) atomicAdd(&deg[ei[NEDGES + e]], 1);
}

__global__ __launch_bounds__(256) void scan_a(
    const int* __restrict__ deg, int* __restrict__ incl, int* __restrict__ bsum)
{
    __shared__ int s[256];
    int t = threadIdx.x, idx = blockIdx.x * 256 + t;
    int v = (idx < NNODES) ? deg[idx] : 0;
    s[t] = v; __syncthreads();
    #pragma unroll
    for (int off = 1; off < 256; off <<= 1) {
        int tmp = (t >= off) ? s[t - off] : 0;
        __syncthreads();
        s[t] += tmp;
        __syncthreads();
    }
    if (idx < NNODES) incl[idx] = s[t];
    if (t == 255) bsum[blockIdx.x] = s[255];
}

__global__ __launch_bounds__(256) void scan_b(
    const int* __restrict__ bsum, int* __restrict__ bscan, int nblk)
{
    __shared__ int s[256];
    int t = threadIdx.x;
    s[t] = (t < nblk) ? bsum[t] : 0; __syncthreads();
    #pragma unroll
    for (int off = 1; off < 256; off <<= 1) {
        int tmp = (t >= off) ? s[t - off] : 0;
        __syncthreads();
        s[t] += tmp;
        __syncthreads();
    }
    bscan[t] = s[t];
}

__global__ __launch_bounds__(256) void scan_c(
    const int* __restrict__ deg, const int* __restrict__ incl,
    const int* __restrict__ bscan,
    int* __restrict__ row_start, int* __restrict__ cur)
{
    int b = blockIdx.x, t = threadIdx.x, idx = b * 256 + t;
    if (idx >= NNODES) return;
    int off = (b > 0) ? bscan[b - 1] : 0;
    int ex = incl[idx] - deg[idx] + off;
    row_start[idx] = ex;
    cur[idx] = ex;
}

// 8 dst-range passes so col[] writes cluster into L2-resident windows.
__global__ __launch_bounds__(256) void edge_fill(
    const int* __restrict__ ei, int* __restrict__ cur, int* __restrict__ col)
{
    int e = blockIdx.x * 256 + threadIdx.x;
    int src = ei[e];
    int dst = ei[NEDGES + e];
    #pragma unroll 1
    for (int p = 0; p < 8; ++p) {
        if (dst / 6250 == p) {
            int pos = atomicAdd(&cur[dst], 1);
            col[pos] = src;
        }
    }
}

// ========== gather (bf16 in/out): H0[i] = (1+eps)*f(Xb[i]) + sum_j f(Xb[col[j]])
// f = BN-scale/shift + ReLU when BN=true. 32 lanes/node, ushort4(8B)/lane.
template<bool BN>
__global__ __launch_bounds__(256) void gin_gather_b(
    const unsigned short* __restrict__ Xb, const int* __restrict__ col,
    const int* __restrict__ rs, const int* __restrict__ re,
    const float* __restrict__ eps,
    const float* __restrict__ scale, const float* __restrict__ shift,
    unsigned short* __restrict__ H0b)
{
    int t = threadIdx.x;
    int node = blockIdx.x * 8 + (t >> 5);
    int lane = t & 31;
    const ushort4* X4 = (const ushort4*)Xb;
    float alpha = 1.f + eps[0];

    float4 sc, sh;
    if (BN) { sc = ((const float4*)scale)[lane]; sh = ((const float4*)shift)[lane]; }

    float4 xi = bf4_to_f4(X4[(long)node * 32 + lane]);
    if (BN) {
        xi.x = fmaxf(fmaf(xi.x, sc.x, sh.x), 0.f);
        xi.y = fmaxf(fmaf(xi.y, sc.y, sh.y), 0.f);
        xi.z = fmaxf(fmaf(xi.z, sc.z, sh.z), 0.f);
        xi.w = fmaxf(fmaf(xi.w, sc.w, sh.w), 0.f);
    }
    float4 acc;
    acc.x = alpha * xi.x; acc.y = alpha * xi.y;
    acc.z = alpha * xi.z; acc.w = alpha * xi.w;

    int j = rs[node], end = re[node];
    for (; j + 3 < end; j += 4) {
        ushort4 u0 = X4[(long)col[j]     * 32 + lane];
        ushort4 u1 = X4[(long)col[j + 1] * 32 + lane];
        ushort4 u2 = X4[(long)col[j + 2] * 32 + lane];
        ushort4 u3 = X4[(long)col[j + 3] * 32 + lane];
        float4 a0 = bf4_to_f4(u0), a1 = bf4_to_f4(u1);
        float4 a2 = bf4_to_f4(u2), a3 = bf4_to_f4(u3);
        if (BN) {
            a0.x = fmaxf(fmaf(a0.x, sc.x, sh.x), 0.f);
            a0.y = fmaxf(fmaf(a0.y, sc.y, sh.y), 0.f);
            a0.z = fmaxf(fmaf(a0.z, sc.z, sh.z), 0.f);
            a0.w = fmaxf(fmaf(a0.w, sc.w, sh.w), 0.f);
            a1.x = fmaxf(fmaf(a1.x, sc.x, sh.x), 0.f);
            a1.y = fmaxf(fmaf(a1.y, sc.y, sh.y), 0.f);
            a1.z = fmaxf(fmaf(a1.z, sc.z, sh.z), 0.f);
            a1.w = fmaxf(fmaf(a1.w, sc.w, sh.w), 0.f);
            a2.x = fmaxf(fmaf(a2.x, sc.x, sh.x), 0.f);
            a2.y = fmaxf(fmaf(a2.y, sc.y, sh.y), 0.f);
            a2.z = fmaxf(fmaf(a2.z, sc.z, sh.z), 0.f);
            a2.w = fmaxf(fmaf(a2.w, sc.w, sh.w), 0.f);
            a3.x = fmaxf(fmaf(a3.x, sc.x, sh.x), 0.f);
            a3.y = fmaxf(fmaf(a3.y, sc.y, sh.y), 0.f);
            a3.z = fmaxf(fmaf(a3.z, sc.z, sh.z), 0.f);
            a3.w = fmaxf(fmaf(a3.w, sc.w, sh.w), 0.f);
        }
        acc.x += (a0.x + a1.x) + (a2.x + a3.x);
        acc.y += (a0.y + a1.y) + (a2.y + a3.y);
        acc.z += (a0.z + a1.z) + (a2.z + a3.z);
        acc.w += (a0.w + a1.w) + (a2.w + a3.w);
    }
    for (; j < end; ++j) {
        float4 a = bf4_to_f4(X4[(long)col[j] * 32 + lane]);
        if (BN) {
            a.x = fmaxf(fmaf(a.x, sc.x, sh.x), 0.f);
            a.y = fmaxf(fmaf(a.y, sc.y, sh.y), 0.f);
            a.z = fmaxf(fmaf(a.z, sc.z, sh.z), 0.f);
            a.w = fmaxf(fmaf(a.w, sc.w, sh.w), 0.f);
        }
        acc.x += a.x; acc.y += a.y; acc.z += a.z; acc.w += a.w;
    }
    ushort4 o;
    o.x = f2bf(acc.x); o.y = f2bf(acc.y); o.z = f2bf(acc.z); o.w = f2bf(acc.w);
    ((ushort4*)H0b)[(long)node * 32 + lane] = o;
}

// ========== MFMA GEMM: C[M,128] = A[M,128] @ W + bias (A,W bf16, acc fp32)
// 64 rows/block = 4 waves x 16-row MFMA tiles. 8 col-tiles in ILP pairs,
// K=128 in 4 chunks of 32. A-frags register-resident; Wt rows L1/L2-hot.
// No LDS, no barriers. Cb (bf16) / Cf (fp32) outputs optional.
template<bool RELU, bool STATS>
__global__ __launch_bounds__(256) void gemm_mfma(
    const unsigned short* __restrict__ A,     // [M][128] bf16
    const unsigned short* __restrict__ Wt,    // [128][128] bf16, N-major (W^T)
    const float* __restrict__ bias,
    unsigned short* __restrict__ Cb,
    float* __restrict__ Cf,
    float* __restrict__ out_sum, float* __restrict__ out_sq)
{
    const int t = threadIdx.x;
    const int wave = t >> 6, lane = t & 63;
    const int m16 = lane & 15, quad = lane >> 4;
    const int row0 = blockIdx.x * 64 + wave * 16;
    const int arow = row0 + m16;

    bf16x8 afrag[4];
    if (arow < NNODES) {
        const unsigned short* ar = A + (long)arow * HD + quad * 8;
        #pragma unroll
        for (int kc = 0; kc < 4; ++kc)
            afrag[kc] = *(const bf16x8*)(ar + kc * 32);
    } else {
        #pragma unroll
        for (int kc = 0; kc < 4; ++kc)
            afrag[kc] = bf16x8{0, 0, 0, 0, 0, 0, 0, 0};
    }

    #pragma unroll
    for (int np = 0; np < 4; ++np) {          // pairs of 16-wide col-tiles
        f32x4 acc0 = {0.f, 0.f, 0.f, 0.f};
        f32x4 acc1 = {0.f, 0.f, 0.f, 0.f};
        const unsigned short* b0 = Wt + (long)(np * 32 + m16) * HD + quad * 8;
        const unsigned short* b1 = b0 + 16 * HD;
        #pragma unroll
        for (int kc = 0; kc < 4; ++kc) {
            bf16x8 bf0 = *(const bf16x8*)(b0 + kc * 32);
            bf16x8 bf1 = *(const bf16x8*)(b1 + kc * 32);
            acc0 = __builtin_amdgcn_mfma_f32_16x16x32_bf16(afrag[kc], bf0, acc0, 0, 0, 0);
            acc1 = __builtin_amdgcn_mfma_f32_16x16x32_bf16(afrag[kc], bf1, acc1, 0, 0, 0);
        }
        #pragma unroll
        for (int h = 0; h < 2; ++h) {
            f32x4 acc = h ? acc1 : acc0;
            const int c = np * 32 + h * 16 + m16;   // C/D: col = lane&15
            float bb = bias[c];
            float tsum = 0.f, tsq = 0.f;
            #pragma unroll
            for (int r = 0; r < 4; ++r) {           // C/D: row = quad*4 + r
                int row = row0 + quad * 4 + r;
                float v = acc[r] + bb;
                if (RELU) v = fmaxf(v, 0.f);
                if (row < NNODES) {
                    if (Cb) Cb[(long)row * HD + c] = f2bf(v);
                    if (Cf) Cf[(long)row * HD + c] = v;
                    if (STATS) { tsum += v; tsq = fmaf(v, v, tsq); }
                }
            }
            if (STATS) {
                tsum += __shfl_xor(tsum, 16); tsq += __shfl_xor(tsq, 16);
                tsum += __shfl_xor(tsum, 32); tsq += __shfl_xor(tsq, 32);
                if (quad == 0) {
                    atomicAdd(&out_sum[c], tsum);
                    atomicAdd(&out_sq[c],  tsq);
                }
            }
        }
    }
}

// ================= BN fold =================
__global__ void bn_prep(const float* __restrict__ ssum, const float* __restrict__ ssq,
                        const float* __restrict__ gamma, const float* __restrict__ beta,
                        float* __restrict__ scale, float* __restrict__ shift)
{
    int c = threadIdx.x;
    const float invN = 1.0f / (float)NNODES;
    float m = ssum[c] * invN;
    float var = fmaf(-m, m, ssq[c] * invN);
    float rs = rsqrtf(var + 1e-5f);
    float sc = gamma[c] * rs;
    scale[c] = sc;
    shift[c] = beta[c] - m * sc;
}

// ========== projection + softmax, BN2+ReLU fused on load ==========
__global__ __launch_bounds__(256) void out_proj_softmax(
    const float* __restrict__ H, const float* __restrict__ Wout,
    const float* __restrict__ scale, const float* __restrict__ shift,
    const float* __restrict__ log_tau,
    float* __restrict__ outS, float* __restrict__ outL)
{
    __shared__ float As[HD][20];
    const int t = threadIdx.x;
    const long row0 = (long)blockIdx.x * 16;

    #pragma unroll
    for (int i = 0; i < 8; ++i) {
        int idx = t + i * 256;
        int r = idx >> 7, cc = idx & 127;
        float v = H[(row0 + r) * HD + cc];
        As[cc][r] = fmaxf(fmaf(v, scale[cc], shift[cc]), 0.f);
    }
    __syncthreads();

    const int c = t & 63;
    const int g = t >> 6;
    float acc[4] = {};

    float wq[8];
    #pragma unroll
    for (int i = 0; i < 8; ++i) wq[i] = Wout[i * KOUT + c];

    #pragma unroll 1
    for (int kc = 0; kc < HD; kc += 8) {
        float wn[8];
        if (kc + 8 < HD) {
            #pragma unroll
            for (int i = 0; i < 8; ++i) wn[i] = Wout[(kc + 8 + i) * KOUT + c];
        }
        #pragma unroll
        for (int i = 0; i < 8; ++i) {
            float4 a = *(const float4*)&As[kc + i][g * 4];
            acc[0] = fmaf(a.x, wq[i], acc[0]);
            acc[1] = fmaf(a.y, wq[i], acc[1]);
            acc[2] = fmaf(a.z, wq[i], acc[2]);
            acc[3] = fmaf(a.w, wq[i], acc[3]);
        }
        if (kc + 8 < HD) {
            #pragma unroll
            for (int i = 0; i < 8; ++i) wq[i] = wn[i];
        }
    }

    float inv_tau = __expf(-log_tau[0]);
    #pragma unroll
    for (int i = 0; i < 4; ++i) {
        float z = acc[i] * inv_tau;
        float m = z;
        #pragma unroll
        for (int o = 32; o > 0; o >>= 1) m = fmaxf(m, __shfl_xor(m, o));
        float e = __expf(z - m);
        float s = e;
        #pragma unroll
        for (int o = 32; o > 0; o >>= 1) s += __shfl_xor(s, o);
        long oi = (row0 + g * 4 + i) * KOUT + c;
        outS[oi] = e / s;
        outL[oi] = acc[i];
    }
}

extern "C" void kernel_launch(void* const* d_in, const int* in_sizes, int n_in,
                              void* d_out, int out_size, void* d_ws, size_t ws_size,
                              hipStream_t stream)
{
    const float* x      = (const float*)d_in[0];
    const int*   ei     = (const int*)d_in[1];
    const float* W1a    = (const float*)d_in[2];
    const float* b1a    = (const float*)d_in[3];
    const float* W1b    = (const float*)d_in[4];
    const float* b1b    = (const float*)d_in[5];
    const float* eps1   = (const float*)d_in[6];
    const float* gamma1 = (const float*)d_in[7];
    const float* beta1  = (const float*)d_in[8];
    const float* W2a    = (const float*)d_in[9];
    const float* b2a    = (const float*)d_in[10];
    const float* W2b    = (const float*)d_in[11];
    const float* b2b    = (const float*)d_in[12];
    const float* eps2   = (const float*)d_in[13];
    const float* gamma2 = (const float*)d_in[14];
    const float* beta2  = (const float*)d_in[15];
    const float* Wout   = (const float*)d_in[16];
    const float* ltau   = (const float*)d_in[17];

    const size_t NB = (size_t)NNODES * HD;
    float* B0 = (float*)d_ws;
    float* B1 = B0 + NB;
    float* B2 = B1 + NB;
    float* ST = B2 + NB;             // stats (1024 floats)
    float* sum1 = ST, *sq1 = ST + 128, *sum2 = ST + 256, *sq2 = ST + 384;
    float* scale1 = ST + 512, *shift1 = ST + 640, *scale2 = ST + 768, *shift2 = ST + 896;

    unsigned short* xb    = (unsigned short*)B2;   // bf16 x   (CSR + gather1)
    unsigned short* h0b   = (unsigned short*)B0;   // gather1 out
    unsigned short* mid1b = (unsigned short*)B2;   // gemm1 out
    unsigned short* hb    = (unsigned short*)B0;   // h1 bf16 (gemm2 out)
    unsigned short* h2b   = (unsigned short*)B2;   // gather2 out
    unsigned short* mid2b = (unsigned short*)B0;   // gemm3 out

    int* I0        = (int*)(ST + 1024);
    int* deg       = I0;
    int* incl      = I0 + 50048;
    int* row_start = I0 + 2 * 50048;
    int* cur       = I0 + 3 * 50048;
    int* bsum      = I0 + 4 * 50048;
    int* bscan     = bsum + 256;
    int* col       = bscan + 256;               // NEDGES ints
    unsigned short* wt1a = (unsigned short*)(col + NEDGES);  // 4 x 128x128 bf16
    unsigned short* wt1b = wt1a + HD * HD;
    unsigned short* wt2a = wt1b + HD * HD;
    unsigned short* wt2b = wt2a + HD * HD;

    const int SCAN_BLKS = (NNODES + 255) / 256;   // 196
    const int GEMM_BLKS = (NNODES + 63) / 64;     // 782

    hipMemsetAsync(ST, 0, 512 * sizeof(float), stream);
    hipMemsetAsync(deg, 0, NNODES * sizeof(int), stream);
    to_bf16<<<NNODES * HD / 1024, 256, 0, stream>>>(x, xb);
    transpose_bf16<<<64, 256, 0, stream>>>(W1a, wt1a);
    transpose_bf16<<<64, 256, 0, stream>>>(W1b, wt1b);
    transpose_bf16<<<64, 256, 0, stream>>>(W2a, wt2a);
    transpose_bf16<<<64, 256, 0, stream>>>(W2b, wt2b);
    edge_hist<<<(NEDGES + 255) / 256, 256, 0, stream>>>(ei, deg);
    scan_a<<<SCAN_BLKS, 256, 0, stream>>>(deg, incl, bsum);
    scan_b<<<1, 256, 0, stream>>>(bsum, bscan, SCAN_BLKS);
    scan_c<<<SCAN_BLKS, 256, 0, stream>>>(deg, incl, bscan, row_start, cur);
    edge_fill<<<NEDGES / 256, 256, 0, stream>>>(ei, cur, col);

    // ---- layer 1
    gin_gather_b<false><<<NNODES / 8, 256, 0, stream>>>(
        xb, col, row_start, cur, eps1, nullptr, nullptr, h0b);
    gemm_mfma<true,  false><<<GEMM_BLKS, 256, 0, stream>>>(
        h0b, wt1a, b1a, mid1b, nullptr, nullptr, nullptr);
    gemm_mfma<false, true ><<<GEMM_BLKS, 256, 0, stream>>>(
        mid1b, wt1b, b1b, hb, nullptr, sum1, sq1);
    bn_prep<<<1, 128, 0, stream>>>(sum1, sq1, gamma1, beta1, scale1, shift1);

    // ---- layer 2 (BN1+ReLU fused into gather reads)
    gin_gather_b<true><<<NNODES / 8, 256, 0, stream>>>(
        hb, col, row_start, cur, eps2, scale1, shift1, h2b);
    gemm_mfma<true,  false><<<GEMM_BLKS, 256, 0, stream>>>(
        h2b, wt2a, b2a, mid2b, nullptr, nullptr, nullptr);
    gemm_mfma<false, true ><<<GEMM_BLKS, 256, 0, stream>>>(
        mid2b, wt2b, b2b, nullptr, B1, sum2, sq2);
    bn_prep<<<1, 128, 0, stream>>>(sum2, sq2, gamma2, beta2, scale2, shift2);

    // ---- projection + softmax (BN2+ReLU fused on load)
    out_proj_softmax<<<NNODES / 16, 256, 0, stream>>>(
        B1, Wout, scale2, shift2, ltau,
        (float*)d_out, (float*)d_out + (size_t)NNODES * KOUT);
}

// Round 10
// 389.221 us; speedup vs baseline: 1.7007x; 1.7007x over previous
//
#include <hip/hip_runtime.h>
#include <hip/hip_bf16.h>

// GIN 2-layer + BN + softmax pipeline for MI355X. All tensors fp32; edges int32.
// R10: MFMA GEMM redone per m33 pattern -- Wt staged ONCE in LDS (barrier-free
// k-loop, ds_read_b128 B-frags), C-tile staged fp32 in LDS overlaying Ws, then
// coalesced vector stores. R9's scattered global B-loads/2B-stores eliminated.
//
// Workspace timeline (B0/B1/B2 = 25.6 MB fp32 regions; b* = bf16 aliases):
//   to_bf16:  xb=(u16*)B2  <- x
//   gather1:  reads xb(B2)    -> H0b=(u16*)B0
//   gemm1:    A=H0b(B0)       -> mid1b=(u16*)B2 (ReLU; kills xb, OK)
//   gemm2s:   A=mid1b(B2)     -> hb=(u16*)B0 + stats1 (kills H0b, OK)
//   gather2:  reads hb(B0)+BN -> H2b=(u16*)B2 (kills mid1b, OK)
//   gemm3:    A=H2b(B2)       -> mid2b=(u16*)B0 (ReLU; kills hb, OK)
//   gemm4s:   A=mid2b(B0)     -> h2 fp32 = B1 + stats2
//   out_proj: reads B1 (+BN2 fused)

#define NNODES 50000
#define NEDGES 800000
#define HD 128
#define KOUT 64

typedef __attribute__((ext_vector_type(8))) short bf16x8;
typedef __attribute__((ext_vector_type(4))) float f32x4;

__device__ __forceinline__ unsigned short f2bf(float f) {   // RNE bf16
    unsigned u = __float_as_uint(f);
    u += 0x7fffu + ((u >> 16) & 1u);
    return (unsigned short)(u >> 16);
}
__device__ __forceinline__ float4 bf4_to_f4(ushort4 u) {
    float4 v;
    v.x = __uint_as_float((unsigned)u.x << 16);
    v.y = __uint_as_float((unsigned)u.y << 16);
    v.z = __uint_as_float((unsigned)u.z << 16);
    v.w = __uint_as_float((unsigned)u.w << 16);
    return v;
}

// ================= fp32 -> bf16 copy =================
__global__ __launch_bounds__(256) void to_bf16(
    const float* __restrict__ in, unsigned short* __restrict__ out)
{
    int i = blockIdx.x * 256 + threadIdx.x;     // float4 index
    float4 v = ((const float4*)in)[i];
    ushort4 o;
    o.x = f2bf(v.x); o.y = f2bf(v.y); o.z = f2bf(v.z); o.w = f2bf(v.w);
    ((ushort4*)out)[i] = o;
}

// ============ weight transpose to bf16: Wt[n][k] = bf16(W[k][n]) ============
__global__ __launch_bounds__(256) void transpose_bf16(
    const float* __restrict__ W, unsigned short* __restrict__ Wt)
{
    int idx = blockIdx.x * 256 + threadIdx.x;   // 0 .. 128*128
    int n = idx >> 7, k = idx & 127;
    Wt[idx] = f2bf(W[k * HD + n]);
}

// ================= CSR build =================
__global__ __launch_bounds__(256) void edge_hist(
    const int* __restrict__ ei, int* __restrict__ deg)
{
    int e = blockIdx.x * 256 + threadIdx.x;
    if (e < NEDGES) atomicAdd(&deg[ei[NEDGES + e]], 1);
}

__global__ __launch_bounds__(256) void scan_a(
    const int* __restrict__ deg, int* __restrict__ incl, int* __restrict__ bsum)
{
    __shared__ int s[256];
    int t = threadIdx.x, idx = blockIdx.x * 256 + t;
    int v = (idx < NNODES) ? deg[idx] : 0;
    s[t] = v; __syncthreads();
    #pragma unroll
    for (int off = 1; off < 256; off <<= 1) {
        int tmp = (t >= off) ? s[t - off] : 0;
        __syncthreads();
        s[t] += tmp;
        __syncthreads();
    }
    if (idx < NNODES) incl[idx] = s[t];
    if (t == 255) bsum[blockIdx.x] = s[255];
}

__global__ __launch_bounds__(256) void scan_b(
    const int* __restrict__ bsum, int* __restrict__ bscan, int nblk)
{
    __shared__ int s[256];
    int t = threadIdx.x;
    s[t] = (t < nblk) ? bsum[t] : 0; __syncthreads();
    #pragma unroll
    for (int off = 1; off < 256; off <<= 1) {
        int tmp = (t >= off) ? s[t - off] : 0;
        __syncthreads();
        s[t] += tmp;
        __syncthreads();
    }
    bscan[t] = s[t];
}

__global__ __launch_bounds__(256) void scan_c(
    const int* __restrict__ deg, const int* __restrict__ incl,
    const int* __restrict__ bscan,
    int* __restrict__ row_start, int* __restrict__ cur)
{
    int b = blockIdx.x, t = threadIdx.x, idx = b * 256 + t;
    if (idx >= NNODES) return;
    int off = (b > 0) ? bscan[b - 1] : 0;
    int ex = incl[idx] - deg[idx] + off;
    row_start[idx] = ex;
    cur[idx] = ex;
}

// 8 dst-range passes so col[] writes cluster into L2-resident windows.
__global__ __launch_bounds__(256) void edge_fill(
    const int* __restrict__ ei, int* __restrict__ cur, int* __restrict__ col)
{
    int e = blockIdx.x * 256 + threadIdx.x;
    int src = ei[e];
    int dst = ei[NEDGES + e];
    #pragma unroll 1
    for (int p = 0; p < 8; ++p) {
        if (dst / 6250 == p) {
            int pos = atomicAdd(&cur[dst], 1);
            col[pos] = src;
        }
    }
}

// ========== gather (bf16 in/out): H0[i] = (1+eps)*f(Xb[i]) + sum_j f(Xb[col[j]])
// f = BN-scale/shift + ReLU when BN=true. 32 lanes/node, ushort4(8B)/lane.
template<bool BN>
__global__ __launch_bounds__(256) void gin_gather_b(
    const unsigned short* __restrict__ Xb, const int* __restrict__ col,
    const int* __restrict__ rs, const int* __restrict__ re,
    const float* __restrict__ eps,
    const float* __restrict__ scale, const float* __restrict__ shift,
    unsigned short* __restrict__ H0b)
{
    int t = threadIdx.x;
    int node = blockIdx.x * 8 + (t >> 5);
    int lane = t & 31;
    const ushort4* X4 = (const ushort4*)Xb;
    float alpha = 1.f + eps[0];

    float4 sc, sh;
    if (BN) { sc = ((const float4*)scale)[lane]; sh = ((const float4*)shift)[lane]; }

    float4 xi = bf4_to_f4(X4[(long)node * 32 + lane]);
    if (BN) {
        xi.x = fmaxf(fmaf(xi.x, sc.x, sh.x), 0.f);
        xi.y = fmaxf(fmaf(xi.y, sc.y, sh.y), 0.f);
        xi.z = fmaxf(fmaf(xi.z, sc.z, sh.z), 0.f);
        xi.w = fmaxf(fmaf(xi.w, sc.w, sh.w), 0.f);
    }
    float4 acc;
    acc.x = alpha * xi.x; acc.y = alpha * xi.y;
    acc.z = alpha * xi.z; acc.w = alpha * xi.w;

    int j = rs[node], end = re[node];
    for (; j + 3 < end; j += 4) {
        ushort4 u0 = X4[(long)col[j]     * 32 + lane];
        ushort4 u1 = X4[(long)col[j + 1] * 32 + lane];
        ushort4 u2 = X4[(long)col[j + 2] * 32 + lane];
        ushort4 u3 = X4[(long)col[j + 3] * 32 + lane];
        float4 a0 = bf4_to_f4(u0), a1 = bf4_to_f4(u1);
        float4 a2 = bf4_to_f4(u2), a3 = bf4_to_f4(u3);
        if (BN) {
            a0.x = fmaxf(fmaf(a0.x, sc.x, sh.x), 0.f);
            a0.y = fmaxf(fmaf(a0.y, sc.y, sh.y), 0.f);
            a0.z = fmaxf(fmaf(a0.z, sc.z, sh.z), 0.f);
            a0.w = fmaxf(fmaf(a0.w, sc.w, sh.w), 0.f);
            a1.x = fmaxf(fmaf(a1.x, sc.x, sh.x), 0.f);
            a1.y = fmaxf(fmaf(a1.y, sc.y, sh.y), 0.f);
            a1.z = fmaxf(fmaf(a1.z, sc.z, sh.z), 0.f);
            a1.w = fmaxf(fmaf(a1.w, sc.w, sh.w), 0.f);
            a2.x = fmaxf(fmaf(a2.x, sc.x, sh.x), 0.f);
            a2.y = fmaxf(fmaf(a2.y, sc.y, sh.y), 0.f);
            a2.z = fmaxf(fmaf(a2.z, sc.z, sh.z), 0.f);
            a2.w = fmaxf(fmaf(a2.w, sc.w, sh.w), 0.f);
            a3.x = fmaxf(fmaf(a3.x, sc.x, sh.x), 0.f);
            a3.y = fmaxf(fmaf(a3.y, sc.y, sh.y), 0.f);
            a3.z = fmaxf(fmaf(a3.z, sc.z, sh.z), 0.f);
            a3.w = fmaxf(fmaf(a3.w, sc.w, sh.w), 0.f);
        }
        acc.x += (a0.x + a1.x) + (a2.x + a3.x);
        acc.y += (a0.y + a1.y) + (a2.y + a3.y);
        acc.z += (a0.z + a1.z) + (a2.z + a3.z);
        acc.w += (a0.w + a1.w) + (a2.w + a3.w);
    }
    for (; j < end; ++j) {
        float4 a = bf4_to_f4(X4[(long)col[j] * 32 + lane]);
        if (BN) {
            a.x = fmaxf(fmaf(a.x, sc.x, sh.x), 0.f);
            a.y = fmaxf(fmaf(a.y, sc.y, sh.y), 0.f);
            a.z = fmaxf(fmaf(a.z, sc.z, sh.z), 0.f);
            a.w = fmaxf(fmaf(a.w, sc.w, sh.w), 0.f);
        }
        acc.x += a.x; acc.y += a.y; acc.z += a.z; acc.w += a.w;
    }
    ushort4 o;
    o.x = f2bf(acc.x); o.y = f2bf(acc.y); o.z = f2bf(acc.z); o.w = f2bf(acc.w);
    ((ushort4*)H0b)[(long)node * 32 + lane] = o;
}

// ========== MFMA GEMM: C[M,128] = A[M,128] @ W + bias (A,W bf16, acc fp32)
// 64 rows/block = 4 waves x 16-row tiles. Wt staged ONCE in LDS (pad 136
// shorts -> balanced banks), B-frags via ds_read_b128; A-frags registers.
// Epilogue: C-tile fp32 in LDS (overlays Ws) -> coalesced vector stores.
template<bool RELU, bool STATS>
__global__ __launch_bounds__(256) void gemm_mfma(
    const unsigned short* __restrict__ A,     // [M][128] bf16
    const unsigned short* __restrict__ Wt,    // [128][128] bf16, N-major (W^T)
    const float* __restrict__ bias,
    unsigned short* __restrict__ Cb,
    float* __restrict__ Cf,
    float* __restrict__ out_sum, float* __restrict__ out_sq)
{
    __shared__ unsigned short Ws[128][136];   // 34816 B; overlaid by Cs after k-loop
    __shared__ float red[2][8][128];          // 8192 B (STATS reduction)
    float (*Cs)[132] = (float(*)[132]) & Ws[0][0];  // 64x132 fp32 = 33792 B <= Ws

    const int t = threadIdx.x;
    const int wave = t >> 6, lane = t & 63;
    const int m16 = lane & 15, quad = lane >> 4;
    const int row0 = blockIdx.x * 64;
    const int arow = row0 + wave * 16 + m16;

    // ---- stage Wt -> Ws (coalesced float4 reads, balanced LDS writes)
    #pragma unroll
    for (int i = 0; i < 8; ++i) {
        int idx = t + i * 256;                // float4 slot 0..2047
        int r = idx >> 4, s = idx & 15;
        *(float4*)&Ws[r][s * 8] = ((const float4*)Wt)[idx];
    }

    // ---- A-fragments (registers; streaming global reads)
    bf16x8 afrag[4];
    if (arow < NNODES) {
        const unsigned short* ar = A + (long)arow * HD + quad * 8;
        #pragma unroll
        for (int kc = 0; kc < 4; ++kc)
            afrag[kc] = *(const bf16x8*)(ar + kc * 32);
    } else {
        #pragma unroll
        for (int kc = 0; kc < 4; ++kc)
            afrag[kc] = bf16x8{0, 0, 0, 0, 0, 0, 0, 0};
    }
    __syncthreads();

    // ---- barrier-free k-loop: 8 col-tiles in ILP pairs, LDS-fed B-frags
    f32x4 accs[8];
    #pragma unroll
    for (int np = 0; np < 8; np += 2) {
        f32x4 a0 = {0.f, 0.f, 0.f, 0.f};
        f32x4 a1 = {0.f, 0.f, 0.f, 0.f};
        const unsigned short* b0 = &Ws[np * 16 + m16][quad * 8];
        const unsigned short* b1 = &Ws[(np + 1) * 16 + m16][quad * 8];
        #pragma unroll
        for (int kc = 0; kc < 4; ++kc) {
            bf16x8 f0 = *(const bf16x8*)(b0 + kc * 32);
            bf16x8 f1 = *(const bf16x8*)(b1 + kc * 32);
            a0 = __builtin_amdgcn_mfma_f32_16x16x32_bf16(afrag[kc], f0, a0, 0, 0, 0);
            a1 = __builtin_amdgcn_mfma_f32_16x16x32_bf16(afrag[kc], f1, a1, 0, 0, 0);
        }
        accs[np] = a0; accs[np + 1] = a1;
    }
    __syncthreads();     // all Ws reads done -> safe to overlay with Cs

    // ---- C-tile (bias+ReLU) -> LDS fp32 (C/D layout: col=lane&15, row=quad*4+r)
    #pragma unroll
    for (int np = 0; np < 8; ++np) {
        int c = np * 16 + m16;
        float bb = bias[c];
        #pragma unroll
        for (int r = 0; r < 4; ++r) {
            float v = accs[np][r] + bb;
            if (RELU) v = fmaxf(v, 0.f);
            Cs[wave * 16 + quad * 4 + r][c] = v;
        }
    }
    __syncthreads();

    // ---- coalesced readback: thread -> fixed 4-col group, 8 rows
    const int s4 = t & 31;
    const int rb = t >> 5;
    float lsum[4] = {}, lsq[4] = {};
    #pragma unroll
    for (int i = 0; i < 8; ++i) {
        int r = rb + i * 8;
        int row = row0 + r;
        float4 v = *(const float4*)&Cs[r][s4 * 4];
        if (row < NNODES) {
            if (Cb) {
                ushort4 o;
                o.x = f2bf(v.x); o.y = f2bf(v.y);
                o.z = f2bf(v.z); o.w = f2bf(v.w);
                ((ushort4*)Cb)[(long)row * 32 + s4] = o;
            }
            if (Cf) ((float4*)Cf)[(long)row * 32 + s4] = v;
            if (STATS) {
                lsum[0] += v.x; lsum[1] += v.y; lsum[2] += v.z; lsum[3] += v.w;
                lsq[0] = fmaf(v.x, v.x, lsq[0]);
                lsq[1] = fmaf(v.y, v.y, lsq[1]);
                lsq[2] = fmaf(v.z, v.z, lsq[2]);
                lsq[3] = fmaf(v.w, v.w, lsq[3]);
            }
        }
    }
    if (STATS) {
        #pragma unroll
        for (int j = 0; j < 4; ++j) {
            red[0][rb][s4 * 4 + j] = lsum[j];
            red[1][rb][s4 * 4 + j] = lsq[j];
        }
        __syncthreads();
        if (t < 128) {
            float s = 0.f, q = 0.f;
            #pragma unroll
            for (int g = 0; g < 8; ++g) { s += red[0][g][t]; q += red[1][g][t]; }
            atomicAdd(&out_sum[t], s);
            atomicAdd(&out_sq[t],  q);
        }
    }
}

// ================= BN fold =================
__global__ void bn_prep(const float* __restrict__ ssum, const float* __restrict__ ssq,
                        const float* __restrict__ gamma, const float* __restrict__ beta,
                        float* __restrict__ scale, float* __restrict__ shift)
{
    int c = threadIdx.x;
    const float invN = 1.0f / (float)NNODES;
    float m = ssum[c] * invN;
    float var = fmaf(-m, m, ssq[c] * invN);
    float rs = rsqrtf(var + 1e-5f);
    float sc = gamma[c] * rs;
    scale[c] = sc;
    shift[c] = beta[c] - m * sc;
}

// ========== projection + softmax, BN2+ReLU fused on load ==========
__global__ __launch_bounds__(256) void out_proj_softmax(
    const float* __restrict__ H, const float* __restrict__ Wout,
    const float* __restrict__ scale, const float* __restrict__ shift,
    const float* __restrict__ log_tau,
    float* __restrict__ outS, float* __restrict__ outL)
{
    __shared__ float As[HD][20];
    const int t = threadIdx.x;
    const long row0 = (long)blockIdx.x * 16;

    #pragma unroll
    for (int i = 0; i < 8; ++i) {
        int idx = t + i * 256;
        int r = idx >> 7, cc = idx & 127;
        float v = H[(row0 + r) * HD + cc];
        As[cc][r] = fmaxf(fmaf(v, scale[cc], shift[cc]), 0.f);
    }
    __syncthreads();

    const int c = t & 63;
    const int g = t >> 6;
    float acc[4] = {};

    float wq[8];
    #pragma unroll
    for (int i = 0; i < 8; ++i) wq[i] = Wout[i * KOUT + c];

    #pragma unroll 1
    for (int kc = 0; kc < HD; kc += 8) {
        float wn[8];
        if (kc + 8 < HD) {
            #pragma unroll
            for (int i = 0; i < 8; ++i) wn[i] = Wout[(kc + 8 + i) * KOUT + c];
        }
        #pragma unroll
        for (int i = 0; i < 8; ++i) {
            float4 a = *(const float4*)&As[kc + i][g * 4];
            acc[0] = fmaf(a.x, wq[i], acc[0]);
            acc[1] = fmaf(a.y, wq[i], acc[1]);
            acc[2] = fmaf(a.z, wq[i], acc[2]);
            acc[3] = fmaf(a.w, wq[i], acc[3]);
        }
        if (kc + 8 < HD) {
            #pragma unroll
            for (int i = 0; i < 8; ++i) wq[i] = wn[i];
        }
    }

    float inv_tau = __expf(-log_tau[0]);
    #pragma unroll
    for (int i = 0; i < 4; ++i) {
        float z = acc[i] * inv_tau;
        float m = z;
        #pragma unroll
        for (int o = 32; o > 0; o >>= 1) m = fmaxf(m, __shfl_xor(m, o));
        float e = __expf(z - m);
        float s = e;
        #pragma unroll
        for (int o = 32; o > 0; o >>= 1) s += __shfl_xor(s, o);
        long oi = (row0 + g * 4 + i) * KOUT + c;
        outS[oi] = e / s;
        outL[oi] = acc[i];
    }
}

extern "C" void kernel_launch(void* const* d_in, const int* in_sizes, int n_in,
                              void* d_out, int out_size, void* d_ws, size_t ws_size,
                              hipStream_t stream)
{
    const float* x      = (const float*)d_in[0];
    const int*   ei     = (const int*)d_in[1];
    const float* W1a    = (const float*)d_in[2];
    const float* b1a    = (const float*)d_in[3];
    const float* W1b    = (const float*)d_in[4];
    const float* b1b    = (const float*)d_in[5];
    const float* eps1   = (const float*)d_in[6];
    const float* gamma1 = (const float*)d_in[7];
    const float* beta1  = (const float*)d_in[8];
    const float* W2a    = (const float*)d_in[9];
    const float* b2a    = (const float*)d_in[10];
    const float* W2b    = (const float*)d_in[11];
    const float* b2b    = (const float*)d_in[12];
    const float* eps2   = (const float*)d_in[13];
    const float* gamma2 = (const float*)d_in[14];
    const float* beta2  = (const float*)d_in[15];
    const float* Wout   = (const float*)d_in[16];
    const float* ltau   = (const float*)d_in[17];

    const size_t NB = (size_t)NNODES * HD;
    float* B0 = (float*)d_ws;
    float* B1 = B0 + NB;
    float* B2 = B1 + NB;
    float* ST = B2 + NB;             // stats (1024 floats)
    float* sum1 = ST, *sq1 = ST + 128, *sum2 = ST + 256, *sq2 = ST + 384;
    float* scale1 = ST + 512, *shift1 = ST + 640, *scale2 = ST + 768, *shift2 = ST + 896;

    unsigned short* xb    = (unsigned short*)B2;   // bf16 x   (CSR + gather1)
    unsigned short* h0b   = (unsigned short*)B0;   // gather1 out
    unsigned short* mid1b = (unsigned short*)B2;   // gemm1 out
    unsigned short* hb    = (unsigned short*)B0;   // h1 bf16 (gemm2 out)
    unsigned short* h2b   = (unsigned short*)B2;   // gather2 out
    unsigned short* mid2b = (unsigned short*)B0;   // gemm3 out

    int* I0        = (int*)(ST + 1024);
    int* deg       = I0;
    int* incl      = I0 + 50048;
    int* row_start = I0 + 2 * 50048;
    int* cur       = I0 + 3 * 50048;
    int* bsum      = I0 + 4 * 50048;
    int* bscan     = bsum + 256;
    int* col       = bscan + 256;               // NEDGES ints
    unsigned short* wt1a = (unsigned short*)(col + NEDGES);  // 4 x 128x128 bf16
    unsigned short* wt1b = wt1a + HD * HD;
    unsigned short* wt2a = wt1b + HD * HD;
    unsigned short* wt2b = wt2a + HD * HD;

    const int SCAN_BLKS = (NNODES + 255) / 256;   // 196
    const int GEMM_BLKS = (NNODES + 63) / 64;     // 782

    hipMemsetAsync(ST, 0, 512 * sizeof(float), stream);
    hipMemsetAsync(deg, 0, NNODES * sizeof(int), stream);
    to_bf16<<<NNODES * HD / 1024, 256, 0, stream>>>(x, xb);
    transpose_bf16<<<64, 256, 0, stream>>>(W1a, wt1a);
    transpose_bf16<<<64, 256, 0, stream>>>(W1b, wt1b);
    transpose_bf16<<<64, 256, 0, stream>>>(W2a, wt2a);
    transpose_bf16<<<64, 256, 0, stream>>>(W2b, wt2b);
    edge_hist<<<(NEDGES + 255) / 256, 256, 0, stream>>>(ei, deg);
    scan_a<<<SCAN_BLKS, 256, 0, stream>>>(deg, incl, bsum);
    scan_b<<<1, 256, 0, stream>>>(bsum, bscan, SCAN_BLKS);
    scan_c<<<SCAN_BLKS, 256, 0, stream>>>(deg, incl, bscan, row_start, cur);
    edge_fill<<<NEDGES / 256, 256, 0, stream>>>(ei, cur, col);

    // ---- layer 1
    gin_gather_b<false><<<NNODES / 8, 256, 0, stream>>>(
        xb, col, row_start, cur, eps1, nullptr, nullptr, h0b);
    gemm_mfma<true,  false><<<GEMM_BLKS, 256, 0, stream>>>(
        h0b, wt1a, b1a, mid1b, nullptr, nullptr, nullptr);
    gemm_mfma<false, true ><<<GEMM_BLKS, 256, 0, stream>>>(
        mid1b, wt1b, b1b, hb, nullptr, sum1, sq1);
    bn_prep<<<1, 128, 0, stream>>>(sum1, sq1, gamma1, beta1, scale1, shift1);

    // ---- layer 2 (BN1+ReLU fused into gather reads)
    gin_gather_b<true><<<NNODES / 8, 256, 0, stream>>>(
        hb, col, row_start, cur, eps2, scale1, shift1, h2b);
    gemm_mfma<true,  false><<<GEMM_BLKS, 256, 0, stream>>>(
        h2b, wt2a, b2a, mid2b, nullptr, nullptr, nullptr);
    gemm_mfma<false, true ><<<GEMM_BLKS, 256, 0, stream>>>(
        mid2b, wt2b, b2b, nullptr, B1, sum2, sq2);
    bn_prep<<<1, 128, 0, stream>>>(sum2, sq2, gamma2, beta2, scale2, shift2);

    // ---- projection + softmax (BN2+ReLU fused on load)
    out_proj_softmax<<<NNODES / 16, 256, 0, stream>>>(
        B1, Wout, scale2, shift2, ltau,
        (float*)d_out, (float*)d_out + (size_t)NNODES * KOUT);
}

// Round 11
// 347.357 us; speedup vs baseline: 1.9057x; 1.1205x over previous
//
#include <hip/hip_runtime.h>
#include <hip/hip_bf16.h>

// GIN 2-layer + BN + softmax pipeline for MI355X. All tensors fp32; edges int32.
// R11: (1) edge_fill XCD-partitioned (class=blockIdx&7 owns one 400KB col
// window -> single-L2 write accumulation); (2) per-layer GEMM pairs fused into
// one MFMA kernel (mid tile stays in LDS, 51MB traffic + 2 dispatches saved);
// (3) to_bf16 + weight transposes merged into prep_all.
//
// Workspace timeline (B0/B1/B2 = 25.6 MB fp32 regions; b* = bf16 aliases):
//   prep_all: xb=(u16*)B2 <- x ; wt* <- W*
//   gather1:  reads xb(B2)    -> h0b=(u16*)B0
//   mlp1:     A=h0b(B0)       -> hb=(u16*)B0 IN-PLACE (row-blocks disjoint) + stats1
//   gather2:  reads hb(B0)+BN -> h2b=(u16*)B2 (kills xb, OK)
//   mlp2:     A=h2b(B2)       -> h2 fp32 = B1 + stats2
//   out_proj: reads B1 (+BN2 fused)

#define NNODES 50000
#define NEDGES 800000
#define HD 128
#define KOUT 64

typedef __attribute__((ext_vector_type(8))) short bf16x8;
typedef __attribute__((ext_vector_type(4))) float f32x4;

__device__ __forceinline__ unsigned short f2bf(float f) {   // RNE bf16
    unsigned u = __float_as_uint(f);
    u += 0x7fffu + ((u >> 16) & 1u);
    return (unsigned short)(u >> 16);
}
__device__ __forceinline__ float4 bf4_to_f4(ushort4 u) {
    float4 v;
    v.x = __uint_as_float((unsigned)u.x << 16);
    v.y = __uint_as_float((unsigned)u.y << 16);
    v.z = __uint_as_float((unsigned)u.z << 16);
    v.w = __uint_as_float((unsigned)u.w << 16);
    return v;
}

// ============ prep: x -> bf16 copy, and 4 weight transposes (bf16) ============
__global__ __launch_bounds__(256) void prep_all(
    const float* __restrict__ x, unsigned short* __restrict__ xb,
    const float* __restrict__ W1a, const float* __restrict__ W1b,
    const float* __restrict__ W2a, const float* __restrict__ W2b,
    unsigned short* __restrict__ wt1a, unsigned short* __restrict__ wt1b,
    unsigned short* __restrict__ wt2a, unsigned short* __restrict__ wt2b)
{
    int bid = blockIdx.x;
    if (bid < 6250) {                       // x -> bf16 (float4 per thread)
        int i = bid * 256 + threadIdx.x;
        float4 v = ((const float4*)x)[i];
        ushort4 o;
        o.x = f2bf(v.x); o.y = f2bf(v.y); o.z = f2bf(v.z); o.w = f2bf(v.w);
        ((ushort4*)xb)[i] = o;
    } else {                                // Wt[n][k] = bf16(W[k][n])
        int wb = bid - 6250;                // 0..255
        int w = wb >> 6;
        int idx = (wb & 63) * 256 + threadIdx.x;   // 0..16383
        int n = idx >> 7, k = idx & 127;
        const float* W = (w == 0) ? W1a : (w == 1) ? W1b : (w == 2) ? W2a : W2b;
        unsigned short* Wt = (w == 0) ? wt1a : (w == 1) ? wt1b : (w == 2) ? wt2a : wt2b;
        Wt[idx] = f2bf(W[k * HD + n]);
    }
}

// ================= CSR build =================
__global__ __launch_bounds__(256) void edge_hist(
    const int* __restrict__ ei, int* __restrict__ deg)
{
    int e = blockIdx.x * 256 + threadIdx.x;
    if (e < NEDGES) atomicAdd(&deg[ei[NEDGES + e]], 1);
}

__global__ __launch_bounds__(256) void scan_a(
    const int* __restrict__ deg, int* __restrict__ incl, int* __restrict__ bsum)
{
    __shared__ int s[256];
    int t = threadIdx.x, idx = blockIdx.x * 256 + t;
    int v = (idx < NNODES) ? deg[idx] : 0;
    s[t] = v; __syncthreads();
    #pragma unroll
    for (int off = 1; off < 256; off <<= 1) {
        int tmp = (t >= off) ? s[t - off] : 0;
        __syncthreads();
        s[t] += tmp;
        __syncthreads();
    }
    if (idx < NNODES) incl[idx] = s[t];
    if (t == 255) bsum[blockIdx.x] = s[255];
}

__global__ __launch_bounds__(256) void scan_b(
    const int* __restrict__ bsum, int* __restrict__ bscan, int nblk)
{
    __shared__ int s[256];
    int t = threadIdx.x;
    s[t] = (t < nblk) ? bsum[t] : 0; __syncthreads();
    #pragma unroll
    for (int off = 1; off < 256; off <<= 1) {
        int tmp = (t >= off) ? s[t - off] : 0;
        __syncthreads();
        s[t] += tmp;
        __syncthreads();
    }
    bscan[t] = s[t];
}

__global__ __launch_bounds__(256) void scan_c(
    const int* __restrict__ deg, const int* __restrict__ incl,
    const int* __restrict__ bscan,
    int* __restrict__ row_start, int* __restrict__ cur)
{
    int b = blockIdx.x, t = threadIdx.x, idx = b * 256 + t;
    if (idx >= NNODES) return;
    int off = (b > 0) ? bscan[b - 1] : 0;
    int ex = incl[idx] - deg[idx] + off;
    row_start[idx] = ex;
    cur[idx] = ex;
}

// XCD-partitioned fill: 256 chunks x 8 classes. Block b scans chunk b>>3,
// processes only dst-range class b&7. With blockIdx%8 -> XCD round-robin,
// each 400KB col window is written by ONE XCD's L2 -> lines accumulate.
__global__ __launch_bounds__(256) void edge_fill(
    const int* __restrict__ ei, int* __restrict__ cur, int* __restrict__ col)
{
    const int cls = blockIdx.x & 7;
    const int e0 = (blockIdx.x >> 3) * 3125;
    for (int e = e0 + threadIdx.x; e < e0 + 3125; e += 256) {
        int dst = ei[NEDGES + e];
        if (dst / 6250 == cls) {
            int pos = atomicAdd(&cur[dst], 1);
            col[pos] = ei[e];
        }
    }
}

// ========== gather (bf16 in/out): H0[i] = (1+eps)*f(Xb[i]) + sum_j f(Xb[col[j]])
// f = BN-scale/shift + ReLU when BN=true. 32 lanes/node, ushort4(8B)/lane.
template<bool BN>
__global__ __launch_bounds__(256) void gin_gather_b(
    const unsigned short* __restrict__ Xb, const int* __restrict__ col,
    const int* __restrict__ rs, const int* __restrict__ re,
    const float* __restrict__ eps,
    const float* __restrict__ scale, const float* __restrict__ shift,
    unsigned short* __restrict__ H0b)
{
    int t = threadIdx.x;
    int node = blockIdx.x * 8 + (t >> 5);
    int lane = t & 31;
    const ushort4* X4 = (const ushort4*)Xb;
    float alpha = 1.f + eps[0];

    float4 sc, sh;
    if (BN) { sc = ((const float4*)scale)[lane]; sh = ((const float4*)shift)[lane]; }

    float4 xi = bf4_to_f4(X4[(long)node * 32 + lane]);
    if (BN) {
        xi.x = fmaxf(fmaf(xi.x, sc.x, sh.x), 0.f);
        xi.y = fmaxf(fmaf(xi.y, sc.y, sh.y), 0.f);
        xi.z = fmaxf(fmaf(xi.z, sc.z, sh.z), 0.f);
        xi.w = fmaxf(fmaf(xi.w, sc.w, sh.w), 0.f);
    }
    float4 acc;
    acc.x = alpha * xi.x; acc.y = alpha * xi.y;
    acc.z = alpha * xi.z; acc.w = alpha * xi.w;

    int j = rs[node], end = re[node];
    for (; j + 3 < end; j += 4) {
        ushort4 u0 = X4[(long)col[j]     * 32 + lane];
        ushort4 u1 = X4[(long)col[j + 1] * 32 + lane];
        ushort4 u2 = X4[(long)col[j + 2] * 32 + lane];
        ushort4 u3 = X4[(long)col[j + 3] * 32 + lane];
        float4 a0 = bf4_to_f4(u0), a1 = bf4_to_f4(u1);
        float4 a2 = bf4_to_f4(u2), a3 = bf4_to_f4(u3);
        if (BN) {
            a0.x = fmaxf(fmaf(a0.x, sc.x, sh.x), 0.f);
            a0.y = fmaxf(fmaf(a0.y, sc.y, sh.y), 0.f);
            a0.z = fmaxf(fmaf(a0.z, sc.z, sh.z), 0.f);
            a0.w = fmaxf(fmaf(a0.w, sc.w, sh.w), 0.f);
            a1.x = fmaxf(fmaf(a1.x, sc.x, sh.x), 0.f);
            a1.y = fmaxf(fmaf(a1.y, sc.y, sh.y), 0.f);
            a1.z = fmaxf(fmaf(a1.z, sc.z, sh.z), 0.f);
            a1.w = fmaxf(fmaf(a1.w, sc.w, sh.w), 0.f);
            a2.x = fmaxf(fmaf(a2.x, sc.x, sh.x), 0.f);
            a2.y = fmaxf(fmaf(a2.y, sc.y, sh.y), 0.f);
            a2.z = fmaxf(fmaf(a2.z, sc.z, sh.z), 0.f);
            a2.w = fmaxf(fmaf(a2.w, sc.w, sh.w), 0.f);
            a3.x = fmaxf(fmaf(a3.x, sc.x, sh.x), 0.f);
            a3.y = fmaxf(fmaf(a3.y, sc.y, sh.y), 0.f);
            a3.z = fmaxf(fmaf(a3.z, sc.z, sh.z), 0.f);
            a3.w = fmaxf(fmaf(a3.w, sc.w, sh.w), 0.f);
        }
        acc.x += (a0.x + a1.x) + (a2.x + a3.x);
        acc.y += (a0.y + a1.y) + (a2.y + a3.y);
        acc.z += (a0.z + a1.z) + (a2.z + a3.z);
        acc.w += (a0.w + a1.w) + (a2.w + a3.w);
    }
    for (; j < end; ++j) {
        float4 a = bf4_to_f4(X4[(long)col[j] * 32 + lane]);
        if (BN) {
            a.x = fmaxf(fmaf(a.x, sc.x, sh.x), 0.f);
            a.y = fmaxf(fmaf(a.y, sc.y, sh.y), 0.f);
            a.z = fmaxf(fmaf(a.z, sc.z, sh.z), 0.f);
            a.w = fmaxf(fmaf(a.w, sc.w, sh.w), 0.f);
        }
        acc.x += a.x; acc.y += a.y; acc.z += a.z; acc.w += a.w;
    }
    ushort4 o;
    o.x = f2bf(acc.x); o.y = f2bf(acc.y); o.z = f2bf(acc.z); o.w = f2bf(acc.w);
    ((ushort4*)H0b)[(long)node * 32 + lane] = o;
}

// ========== fused MLP: C = (ReLU(A@Wa + ba))@Wb + bb, + per-col stats.
// 64 rows/block = 4 waves x 16-row tiles. Both Wt's staged once in LDS;
// mid tile lives in LDS (overlays Wsa); stats red overlays Wsb.
__global__ __launch_bounds__(256) void mlp_mfma(
    const unsigned short* __restrict__ A,      // [M][128] bf16
    const unsigned short* __restrict__ Wta,    // [128][128] bf16 N-major
    const float* __restrict__ biasa,
    const unsigned short* __restrict__ Wtb,
    const float* __restrict__ biasb,
    unsigned short* __restrict__ Cb,           // optional bf16 out
    float* __restrict__ Cf,                    // optional fp32 out
    float* __restrict__ out_sum, float* __restrict__ out_sq)
{
    __shared__ unsigned short Wsa[128][136];   // 34816 B
    __shared__ unsigned short Wsb[128][136];   // 34816 B
    float (*Cs)[132] = (float(*)[132]) & Wsa[0][0];   // 64x132 fp32 = 33792 B
    float* redp = (float*)&Wsb[0][0];                 // 2*8*128 fp32 = 8192 B

    const int t = threadIdx.x;
    const int wave = t >> 6, lane = t & 63;
    const int m16 = lane & 15, quad = lane >> 4;
    const int row0 = blockIdx.x * 64;
    const int arow = row0 + wave * 16 + m16;

    // stage both weight matrices (coalesced float4)
    #pragma unroll
    for (int i = 0; i < 8; ++i) {
        int idx = t + i * 256;
        int r = idx >> 4, s = idx & 15;
        *(float4*)&Wsa[r][s * 8] = ((const float4*)Wta)[idx];
        *(float4*)&Wsb[r][s * 8] = ((const float4*)Wtb)[idx];
    }

    // A-fragments from global (registers)
    bf16x8 afrag[4];
    if (arow < NNODES) {
        const unsigned short* ar = A + (long)arow * HD + quad * 8;
        #pragma unroll
        for (int kc = 0; kc < 4; ++kc)
            afrag[kc] = *(const bf16x8*)(ar + kc * 32);
    } else {
        #pragma unroll
        for (int kc = 0; kc < 4; ++kc)
            afrag[kc] = bf16x8{0, 0, 0, 0, 0, 0, 0, 0};
    }
    __syncthreads();

    // ---- GEMM 1: mid = A @ Wa
    f32x4 accs[8];
    #pragma unroll
    for (int np = 0; np < 8; np += 2) {
        f32x4 a0 = {0.f, 0.f, 0.f, 0.f};
        f32x4 a1 = {0.f, 0.f, 0.f, 0.f};
        const unsigned short* b0 = &Wsa[np * 16 + m16][quad * 8];
        const unsigned short* b1 = &Wsa[(np + 1) * 16 + m16][quad * 8];
        #pragma unroll
        for (int kc = 0; kc < 4; ++kc) {
            bf16x8 f0 = *(const bf16x8*)(b0 + kc * 32);
            bf16x8 f1 = *(const bf16x8*)(b1 + kc * 32);
            a0 = __builtin_amdgcn_mfma_f32_16x16x32_bf16(afrag[kc], f0, a0, 0, 0, 0);
            a1 = __builtin_amdgcn_mfma_f32_16x16x32_bf16(afrag[kc], f1, a1, 0, 0, 0);
        }
        accs[np] = a0; accs[np + 1] = a1;
    }
    __syncthreads();                      // Wsa reads done -> overlay Cs

    // mid (bias+ReLU) -> Cs (C/D layout: col=lane&15, row=quad*4+r)
    #pragma unroll
    for (int np = 0; np < 8; ++np) {
        int c = np * 16 + m16;
        float bb = biasa[c];
        #pragma unroll
        for (int r = 0; r < 4; ++r)
            Cs[wave * 16 + quad * 4 + r][c] = fmaxf(accs[np][r] + bb, 0.f);
    }
    __syncthreads();

    // ---- GEMM 2: A2-fragments from Cs (fp32 -> bf16 RNE, matches R10 mid1b)
    bf16x8 afrag2[4];
    {
        const int crow = wave * 16 + m16;
        #pragma unroll
        for (int kc = 0; kc < 4; ++kc) {
            const float* cp = &Cs[crow][quad * 8 + kc * 32];
            float4 c0 = *(const float4*)cp;
            float4 c1 = *(const float4*)(cp + 4);
            bf16x8 fr;
            fr[0] = (short)f2bf(c0.x); fr[1] = (short)f2bf(c0.y);
            fr[2] = (short)f2bf(c0.z); fr[3] = (short)f2bf(c0.w);
            fr[4] = (short)f2bf(c1.x); fr[5] = (short)f2bf(c1.y);
            fr[6] = (short)f2bf(c1.z); fr[7] = (short)f2bf(c1.w);
            afrag2[kc] = fr;
        }
    }
    #pragma unroll
    for (int np = 0; np < 8; np += 2) {
        f32x4 a0 = {0.f, 0.f, 0.f, 0.f};
        f32x4 a1 = {0.f, 0.f, 0.f, 0.f};
        const unsigned short* b0 = &Wsb[np * 16 + m16][quad * 8];
        const unsigned short* b1 = &Wsb[(np + 1) * 16 + m16][quad * 8];
        #pragma unroll
        for (int kc = 0; kc < 4; ++kc) {
            bf16x8 f0 = *(const bf16x8*)(b0 + kc * 32);
            bf16x8 f1 = *(const bf16x8*)(b1 + kc * 32);
            a0 = __builtin_amdgcn_mfma_f32_16x16x32_bf16(afrag2[kc], f0, a0, 0, 0, 0);
            a1 = __builtin_amdgcn_mfma_f32_16x16x32_bf16(afrag2[kc], f1, a1, 0, 0, 0);
        }
        accs[np] = a0; accs[np + 1] = a1;
    }
    __syncthreads();                      // Cs-as-A + Wsb reads done

    // h (bias, no ReLU) -> Cs
    #pragma unroll
    for (int np = 0; np < 8; ++np) {
        int c = np * 16 + m16;
        float bb = biasb[c];
        #pragma unroll
        for (int r = 0; r < 4; ++r)
            Cs[wave * 16 + quad * 4 + r][c] = accs[np][r] + bb;
    }
    __syncthreads();

    // coalesced readback + stats (red overlays Wsb)
    const int s4 = t & 31;
    const int rb = t >> 5;
    float lsum[4] = {}, lsq[4] = {};
    #pragma unroll
    for (int i = 0; i < 8; ++i) {
        int r = rb + i * 8;
        int row = row0 + r;
        float4 v = *(const float4*)&Cs[r][s4 * 4];
        if (row < NNODES) {
            if (Cb) {
                ushort4 o;
                o.x = f2bf(v.x); o.y = f2bf(v.y);
                o.z = f2bf(v.z); o.w = f2bf(v.w);
                ((ushort4*)Cb)[(long)row * 32 + s4] = o;
            }
            if (Cf) ((float4*)Cf)[(long)row * 32 + s4] = v;
            lsum[0] += v.x; lsum[1] += v.y; lsum[2] += v.z; lsum[3] += v.w;
            lsq[0] = fmaf(v.x, v.x, lsq[0]);
            lsq[1] = fmaf(v.y, v.y, lsq[1]);
            lsq[2] = fmaf(v.z, v.z, lsq[2]);
            lsq[3] = fmaf(v.w, v.w, lsq[3]);
        }
    }
    #pragma unroll
    for (int j = 0; j < 4; ++j) {
        redp[(0 * 8 + rb) * 128 + s4 * 4 + j] = lsum[j];
        redp[(1 * 8 + rb) * 128 + s4 * 4 + j] = lsq[j];
    }
    __syncthreads();
    if (t < 128) {
        float s = 0.f, q = 0.f;
        #pragma unroll
        for (int g = 0; g < 8; ++g) {
            s += redp[g * 128 + t];
            q += redp[(8 + g) * 128 + t];
        }
        atomicAdd(&out_sum[t], s);
        atomicAdd(&out_sq[t],  q);
    }
}

// ================= BN fold =================
__global__ void bn_prep(const float* __restrict__ ssum, const float* __restrict__ ssq,
                        const float* __restrict__ gamma, const float* __restrict__ beta,
                        float* __restrict__ scale, float* __restrict__ shift)
{
    int c = threadIdx.x;
    const float invN = 1.0f / (float)NNODES;
    float m = ssum[c] * invN;
    float var = fmaf(-m, m, ssq[c] * invN);
    float rs = rsqrtf(var + 1e-5f);
    float sc = gamma[c] * rs;
    scale[c] = sc;
    shift[c] = beta[c] - m * sc;
}

// ========== projection + softmax, BN2+ReLU fused on load ==========
__global__ __launch_bounds__(256) void out_proj_softmax(
    const float* __restrict__ H, const float* __restrict__ Wout,
    const float* __restrict__ scale, const float* __restrict__ shift,
    const float* __restrict__ log_tau,
    float* __restrict__ outS, float* __restrict__ outL)
{
    __shared__ float As[HD][20];
    const int t = threadIdx.x;
    const long row0 = (long)blockIdx.x * 16;

    #pragma unroll
    for (int i = 0; i < 8; ++i) {
        int idx = t + i * 256;
        int r = idx >> 7, cc = idx & 127;
        float v = H[(row0 + r) * HD + cc];
        As[cc][r] = fmaxf(fmaf(v, scale[cc], shift[cc]), 0.f);
    }
    __syncthreads();

    const int c = t & 63;
    const int g = t >> 6;
    float acc[4] = {};

    float wq[8];
    #pragma unroll
    for (int i = 0; i < 8; ++i) wq[i] = Wout[i * KOUT + c];

    #pragma unroll 1
    for (int kc = 0; kc < HD; kc += 8) {
        float wn[8];
        if (kc + 8 < HD) {
            #pragma unroll
            for (int i = 0; i < 8; ++i) wn[i] = Wout[(kc + 8 + i) * KOUT + c];
        }
        #pragma unroll
        for (int i = 0; i < 8; ++i) {
            float4 a = *(const float4*)&As[kc + i][g * 4];
            acc[0] = fmaf(a.x, wq[i], acc[0]);
            acc[1] = fmaf(a.y, wq[i], acc[1]);
            acc[2] = fmaf(a.z, wq[i], acc[2]);
            acc[3] = fmaf(a.w, wq[i], acc[3]);
        }
        if (kc + 8 < HD) {
            #pragma unroll
            for (int i = 0; i < 8; ++i) wq[i] = wn[i];
        }
    }

    float inv_tau = __expf(-log_tau[0]);
    #pragma unroll
    for (int i = 0; i < 4; ++i) {
        float z = acc[i] * inv_tau;
        float m = z;
        #pragma unroll
        for (int o = 32; o > 0; o >>= 1) m = fmaxf(m, __shfl_xor(m, o));
        float e = __expf(z - m);
        float s = e;
        #pragma unroll
        for (int o = 32; o > 0; o >>= 1) s += __shfl_xor(s, o);
        long oi = (row0 + g * 4 + i) * KOUT + c;
        outS[oi] = e / s;
        outL[oi] = acc[i];
    }
}

extern "C" void kernel_launch(void* const* d_in, const int* in_sizes, int n_in,
                              void* d_out, int out_size, void* d_ws, size_t ws_size,
                              hipStream_t stream)
{
    const float* x      = (const float*)d_in[0];
    const int*   ei     = (const int*)d_in[1];
    const float* W1a    = (const float*)d_in[2];
    const float* b1a    = (const float*)d_in[3];
    const float* W1b    = (const float*)d_in[4];
    const float* b1b    = (const float*)d_in[5];
    const float* eps1   = (const float*)d_in[6];
    const float* gamma1 = (const float*)d_in[7];
    const float* beta1  = (const float*)d_in[8];
    const float* W2a    = (const float*)d_in[9];
    const float* b2a    = (const float*)d_in[10];
    const float* W2b    = (const float*)d_in[11];
    const float* b2b    = (const float*)d_in[12];
    const float* eps2   = (const float*)d_in[13];
    const float* gamma2 = (const float*)d_in[14];
    const float* beta2  = (const float*)d_in[15];
    const float* Wout   = (const float*)d_in[16];
    const float* ltau   = (const float*)d_in[17];

    const size_t NB = (size_t)NNODES * HD;
    float* B0 = (float*)d_ws;
    float* B1 = B0 + NB;
    float* B2 = B1 + NB;
    float* ST = B2 + NB;             // stats (1024 floats)
    float* sum1 = ST, *sq1 = ST + 128, *sum2 = ST + 256, *sq2 = ST + 384;
    float* scale1 = ST + 512, *shift1 = ST + 640, *scale2 = ST + 768, *shift2 = ST + 896;

    unsigned short* xb  = (unsigned short*)B2;   // bf16 x (CSR + gather1)
    unsigned short* h0b = (unsigned short*)B0;   // gather1 out; mlp1 in-place -> hb
    unsigned short* hb  = (unsigned short*)B0;   // h1 bf16
    unsigned short* h2b = (unsigned short*)B2;   // gather2 out

    int* I0        = (int*)(ST + 1024);
    int* deg       = I0;
    int* incl      = I0 + 50048;
    int* row_start = I0 + 2 * 50048;
    int* cur       = I0 + 3 * 50048;
    int* bsum      = I0 + 4 * 50048;
    int* bscan     = bsum + 256;
    int* col       = bscan + 256;               // NEDGES ints
    unsigned short* wt1a = (unsigned short*)(col + NEDGES);  // 4 x 128x128 bf16
    unsigned short* wt1b = wt1a + HD * HD;
    unsigned short* wt2a = wt1b + HD * HD;
    unsigned short* wt2b = wt2a + HD * HD;

    const int SCAN_BLKS = (NNODES + 255) / 256;   // 196
    const int GEMM_BLKS = (NNODES + 63) / 64;     // 782

    hipMemsetAsync(ST, 0, 512 * sizeof(float), stream);
    hipMemsetAsync(deg, 0, NNODES * sizeof(int), stream);
    prep_all<<<6506, 256, 0, stream>>>(x, xb, W1a, W1b, W2a, W2b,
                                       wt1a, wt1b, wt2a, wt2b);
    edge_hist<<<(NEDGES + 255) / 256, 256, 0, stream>>>(ei, deg);
    scan_a<<<SCAN_BLKS, 256, 0, stream>>>(deg, incl, bsum);
    scan_b<<<1, 256, 0, stream>>>(bsum, bscan, SCAN_BLKS);
    scan_c<<<SCAN_BLKS, 256, 0, stream>>>(deg, incl, bscan, row_start, cur);
    edge_fill<<<2048, 256, 0, stream>>>(ei, cur, col);

    // ---- layer 1
    gin_gather_b<false><<<NNODES / 8, 256, 0, stream>>>(
        xb, col, row_start, cur, eps1, nullptr, nullptr, h0b);
    mlp_mfma<<<GEMM_BLKS, 256, 0, stream>>>(
        h0b, wt1a, b1a, wt1b, b1b, hb, nullptr, sum1, sq1);
    bn_prep<<<1, 128, 0, stream>>>(sum1, sq1, gamma1, beta1, scale1, shift1);

    // ---- layer 2 (BN1+ReLU fused into gather reads)
    gin_gather_b<true><<<NNODES / 8, 256, 0, stream>>>(
        hb, col, row_start, cur, eps2, scale1, shift1, h2b);
    mlp_mfma<<<GEMM_BLKS, 256, 0, stream>>>(
        h2b, wt2a, b2a, wt2b, b2b, nullptr, B1, sum2, sq2);
    bn_prep<<<1, 128, 0, stream>>>(sum2, sq2, gamma2, beta2, scale2, shift2);

    // ---- projection + softmax (BN2+ReLU fused on load)
    out_proj_softmax<<<NNODES / 16, 256, 0, stream>>>(
        B1, Wout, scale2, shift2, ltau,
        (float*)d_out, (float*)d_out + (size_t)NNODES * KOUT);
}

// Round 12
// 346.486 us; speedup vs baseline: 1.9105x; 1.0025x over previous
//
#include <hip/hip_runtime.h>
#include <hip/hip_bf16.h>

// GIN 2-layer + BN + softmax pipeline for MI355X. All tensors fp32; edges int32.
// R12: gather widened to 16 lanes/node x 16B loads (half the VMEM instrs --
// it's load-issue bound, not bytes-bound), 2 serial nodes/group for degree
// balance; edge_hist folded into prep_all.
//
// Workspace timeline (B0/B1/B2 = 25.6 MB fp32 regions; b* = bf16 aliases):
//   prep_all: xb=(u16*)B2 <- x ; wt* <- W* ; deg histogram
//   gather1:  reads xb(B2)    -> h0b=(u16*)B0
//   mlp1:     A=h0b(B0)       -> hb=(u16*)B0 IN-PLACE (row-blocks disjoint) + stats1
//   gather2:  reads hb(B0)+BN -> h2b=(u16*)B2 (kills xb, OK)
//   mlp2:     A=h2b(B2)       -> h2 fp32 = B1 + stats2
//   out_proj: reads B1 (+BN2 fused)

#define NNODES 50000
#define NEDGES 800000
#define HD 128
#define KOUT 64

typedef __attribute__((ext_vector_type(8))) short bf16x8;
typedef __attribute__((ext_vector_type(4))) float f32x4;

__device__ __forceinline__ unsigned short f2bf(float f) {   // RNE bf16
    unsigned u = __float_as_uint(f);
    u += 0x7fffu + ((u >> 16) & 1u);
    return (unsigned short)(u >> 16);
}
__device__ __forceinline__ float4 bf4_to_f4(ushort4 u) {
    float4 v;
    v.x = __uint_as_float((unsigned)u.x << 16);
    v.y = __uint_as_float((unsigned)u.y << 16);
    v.z = __uint_as_float((unsigned)u.z << 16);
    v.w = __uint_as_float((unsigned)u.w << 16);
    return v;
}
// unpack 8 bf16 (carried in a float4) -> 8 fp32
__device__ __forceinline__ void bf8_unpack(float4 u, float* v) {
    unsigned a = __float_as_uint(u.x), b = __float_as_uint(u.y);
    unsigned c = __float_as_uint(u.z), d = __float_as_uint(u.w);
    v[0] = __uint_as_float(a << 16); v[1] = __uint_as_float(a & 0xffff0000u);
    v[2] = __uint_as_float(b << 16); v[3] = __uint_as_float(b & 0xffff0000u);
    v[4] = __uint_as_float(c << 16); v[5] = __uint_as_float(c & 0xffff0000u);
    v[6] = __uint_as_float(d << 16); v[7] = __uint_as_float(d & 0xffff0000u);
}

// ===== prep: x -> bf16, 4 weight transposes (bf16), edge histogram =====
__global__ __launch_bounds__(256) void prep_all(
    const float* __restrict__ x, unsigned short* __restrict__ xb,
    const float* __restrict__ W1a, const float* __restrict__ W1b,
    const float* __restrict__ W2a, const float* __restrict__ W2b,
    unsigned short* __restrict__ wt1a, unsigned short* __restrict__ wt1b,
    unsigned short* __restrict__ wt2a, unsigned short* __restrict__ wt2b,
    const int* __restrict__ ei, int* __restrict__ deg)
{
    int bid = blockIdx.x;
    if (bid < 6250) {                       // x -> bf16 (float4 per thread)
        int i = bid * 256 + threadIdx.x;
        float4 v = ((const float4*)x)[i];
        ushort4 o;
        o.x = f2bf(v.x); o.y = f2bf(v.y); o.z = f2bf(v.z); o.w = f2bf(v.w);
        ((ushort4*)xb)[i] = o;
    } else if (bid < 6506) {                // Wt[n][k] = bf16(W[k][n])
        int wb = bid - 6250;                // 0..255
        int w = wb >> 6;
        int idx = (wb & 63) * 256 + threadIdx.x;   // 0..16383
        int n = idx >> 7, k = idx & 127;
        const float* W = (w == 0) ? W1a : (w == 1) ? W1b : (w == 2) ? W2a : W2b;
        unsigned short* Wt = (w == 0) ? wt1a : (w == 1) ? wt1b : (w == 2) ? wt2a : wt2b;
        Wt[idx] = f2bf(W[k * HD + n]);
    } else {                                // edge histogram
        int e = (bid - 6506) * 256 + threadIdx.x;
        if (e < NEDGES) atomicAdd(&deg[ei[NEDGES + e]], 1);
    }
}

// ================= CSR build =================
__global__ __launch_bounds__(256) void scan_a(
    const int* __restrict__ deg, int* __restrict__ incl, int* __restrict__ bsum)
{
    __shared__ int s[256];
    int t = threadIdx.x, idx = blockIdx.x * 256 + t;
    int v = (idx < NNODES) ? deg[idx] : 0;
    s[t] = v; __syncthreads();
    #pragma unroll
    for (int off = 1; off < 256; off <<= 1) {
        int tmp = (t >= off) ? s[t - off] : 0;
        __syncthreads();
        s[t] += tmp;
        __syncthreads();
    }
    if (idx < NNODES) incl[idx] = s[t];
    if (t == 255) bsum[blockIdx.x] = s[255];
}

__global__ __launch_bounds__(256) void scan_b(
    const int* __restrict__ bsum, int* __restrict__ bscan, int nblk)
{
    __shared__ int s[256];
    int t = threadIdx.x;
    s[t] = (t < nblk) ? bsum[t] : 0; __syncthreads();
    #pragma unroll
    for (int off = 1; off < 256; off <<= 1) {
        int tmp = (t >= off) ? s[t - off] : 0;
        __syncthreads();
        s[t] += tmp;
        __syncthreads();
    }
    bscan[t] = s[t];
}

__global__ __launch_bounds__(256) void scan_c(
    const int* __restrict__ deg, const int* __restrict__ incl,
    const int* __restrict__ bscan,
    int* __restrict__ row_start, int* __restrict__ cur)
{
    int b = blockIdx.x, t = threadIdx.x, idx = b * 256 + t;
    if (idx >= NNODES) return;
    int off = (b > 0) ? bscan[b - 1] : 0;
    int ex = incl[idx] - deg[idx] + off;
    row_start[idx] = ex;
    cur[idx] = ex;
}

// XCD-partitioned fill: 256 chunks x 8 classes; class = blockIdx&7 owns one
// 400KB col window -> single-L2 write accumulation.
__global__ __launch_bounds__(256) void edge_fill(
    const int* __restrict__ ei, int* __restrict__ cur, int* __restrict__ col)
{
    const int cls = blockIdx.x & 7;
    const int e0 = (blockIdx.x >> 3) * 3125;
    for (int e = e0 + threadIdx.x; e < e0 + 3125; e += 256) {
        int dst = ei[NEDGES + e];
        if (dst / 6250 == cls) {
            int pos = atomicAdd(&cur[dst], 1);
            col[pos] = ei[e];
        }
    }
}

// ========== gather (bf16 in/out), 16 lanes/node x 16B loads ==========
// H0[i] = (1+eps)*f(Xb[i]) + sum_j f(Xb[col[j]]); f = BN+ReLU when BN.
// 2 serial nodes per 16-lane group (32 nodes/block) for degree balance.
template<bool BN>
__global__ __launch_bounds__(256) void gin_gather_w(
    const unsigned short* __restrict__ Xb, const int* __restrict__ col,
    const int* __restrict__ rs, const int* __restrict__ re,
    const float* __restrict__ eps,
    const float* __restrict__ scale, const float* __restrict__ shift,
    unsigned short* __restrict__ H0b)
{
    const int t = threadIdx.x;
    const int g = t >> 4;            // 16 groups
    const int lane = t & 15;         // 16B per lane -> 8 feats
    const float4* X4 = (const float4*)Xb;      // 16 float4 per row
    const float alpha = 1.f + eps[0];

    float sc[8], sh[8];
    if (BN) {
        #pragma unroll
        for (int i = 0; i < 8; ++i) {
            sc[i] = scale[lane * 8 + i];
            sh[i] = shift[lane * 8 + i];
        }
    }

    #pragma unroll 1
    for (int nn = 0; nn < 2; ++nn) {
        int node = blockIdx.x * 32 + nn * 16 + g;
        if (node >= NNODES) continue;

        float acc[8], a0[8], a1[8], a2[8], a3[8];
        bf8_unpack(X4[(long)node * 16 + lane], acc);
        #pragma unroll
        for (int i = 0; i < 8; ++i) {
            if (BN) acc[i] = fmaxf(fmaf(acc[i], sc[i], sh[i]), 0.f);
            acc[i] *= alpha;
        }

        int j = rs[node], end = re[node];
        for (; j + 3 < end; j += 4) {
            float4 u0 = X4[(long)col[j]     * 16 + lane];
            float4 u1 = X4[(long)col[j + 1] * 16 + lane];
            float4 u2 = X4[(long)col[j + 2] * 16 + lane];
            float4 u3 = X4[(long)col[j + 3] * 16 + lane];
            bf8_unpack(u0, a0); bf8_unpack(u1, a1);
            bf8_unpack(u2, a2); bf8_unpack(u3, a3);
            #pragma unroll
            for (int i = 0; i < 8; ++i) {
                float v0 = a0[i], v1 = a1[i], v2 = a2[i], v3 = a3[i];
                if (BN) {
                    v0 = fmaxf(fmaf(v0, sc[i], sh[i]), 0.f);
                    v1 = fmaxf(fmaf(v1, sc[i], sh[i]), 0.f);
                    v2 = fmaxf(fmaf(v2, sc[i], sh[i]), 0.f);
                    v3 = fmaxf(fmaf(v3, sc[i], sh[i]), 0.f);
                }
                acc[i] += (v0 + v1) + (v2 + v3);
            }
        }
        for (; j < end; ++j) {
            bf8_unpack(X4[(long)col[j] * 16 + lane], a0);
            #pragma unroll
            for (int i = 0; i < 8; ++i) {
                float v = a0[i];
                if (BN) v = fmaxf(fmaf(v, sc[i], sh[i]), 0.f);
                acc[i] += v;
            }
        }

        uint4 o;
        o.x = ((unsigned)f2bf(acc[1]) << 16) | f2bf(acc[0]);
        o.y = ((unsigned)f2bf(acc[3]) << 16) | f2bf(acc[2]);
        o.z = ((unsigned)f2bf(acc[5]) << 16) | f2bf(acc[4]);
        o.w = ((unsigned)f2bf(acc[7]) << 16) | f2bf(acc[6]);
        ((uint4*)H0b)[(long)node * 16 + lane] = o;
    }
}

// ========== fused MLP: C = (ReLU(A@Wa + ba))@Wb + bb, + per-col stats ==========
__global__ __launch_bounds__(256) void mlp_mfma(
    const unsigned short* __restrict__ A,      // [M][128] bf16
    const unsigned short* __restrict__ Wta,    // [128][128] bf16 N-major
    const float* __restrict__ biasa,
    const unsigned short* __restrict__ Wtb,
    const float* __restrict__ biasb,
    unsigned short* __restrict__ Cb,           // optional bf16 out
    float* __restrict__ Cf,                    // optional fp32 out
    float* __restrict__ out_sum, float* __restrict__ out_sq)
{
    __shared__ unsigned short Wsa[128][136];   // 34816 B
    __shared__ unsigned short Wsb[128][136];   // 34816 B
    float (*Cs)[132] = (float(*)[132]) & Wsa[0][0];   // 64x132 fp32
    float* redp = (float*)&Wsb[0][0];                 // 2*8*128 fp32

    const int t = threadIdx.x;
    const int wave = t >> 6, lane = t & 63;
    const int m16 = lane & 15, quad = lane >> 4;
    const int row0 = blockIdx.x * 64;
    const int arow = row0 + wave * 16 + m16;

    #pragma unroll
    for (int i = 0; i < 8; ++i) {
        int idx = t + i * 256;
        int r = idx >> 4, s = idx & 15;
        *(float4*)&Wsa[r][s * 8] = ((const float4*)Wta)[idx];
        *(float4*)&Wsb[r][s * 8] = ((const float4*)Wtb)[idx];
    }

    bf16x8 afrag[4];
    if (arow < NNODES) {
        const unsigned short* ar = A + (long)arow * HD + quad * 8;
        #pragma unroll
        for (int kc = 0; kc < 4; ++kc)
            afrag[kc] = *(const bf16x8*)(ar + kc * 32);
    } else {
        #pragma unroll
        for (int kc = 0; kc < 4; ++kc)
            afrag[kc] = bf16x8{0, 0, 0, 0, 0, 0, 0, 0};
    }
    __syncthreads();

    // ---- GEMM 1
    f32x4 accs[8];
    #pragma unroll
    for (int np = 0; np < 8; np += 2) {
        f32x4 a0 = {0.f, 0.f, 0.f, 0.f};
        f32x4 a1 = {0.f, 0.f, 0.f, 0.f};
        const unsigned short* b0 = &Wsa[np * 16 + m16][quad * 8];
        const unsigned short* b1 = &Wsa[(np + 1) * 16 + m16][quad * 8];
        #pragma unroll
        for (int kc = 0; kc < 4; ++kc) {
            bf16x8 f0 = *(const bf16x8*)(b0 + kc * 32);
            bf16x8 f1 = *(const bf16x8*)(b1 + kc * 32);
            a0 = __builtin_amdgcn_mfma_f32_16x16x32_bf16(afrag[kc], f0, a0, 0, 0, 0);
            a1 = __builtin_amdgcn_mfma_f32_16x16x32_bf16(afrag[kc], f1, a1, 0, 0, 0);
        }
        accs[np] = a0; accs[np + 1] = a1;
    }
    __syncthreads();

    #pragma unroll
    for (int np = 0; np < 8; ++np) {
        int c = np * 16 + m16;
        float bb = biasa[c];
        #pragma unroll
        for (int r = 0; r < 4; ++r)
            Cs[wave * 16 + quad * 4 + r][c] = fmaxf(accs[np][r] + bb, 0.f);
    }
    __syncthreads();

    // ---- GEMM 2 (A2 from Cs, fp32 -> bf16 RNE)
    bf16x8 afrag2[4];
    {
        const int crow = wave * 16 + m16;
        #pragma unroll
        for (int kc = 0; kc < 4; ++kc) {
            const float* cp = &Cs[crow][quad * 8 + kc * 32];
            float4 c0 = *(const float4*)cp;
            float4 c1 = *(const float4*)(cp + 4);
            bf16x8 fr;
            fr[0] = (short)f2bf(c0.x); fr[1] = (short)f2bf(c0.y);
            fr[2] = (short)f2bf(c0.z); fr[3] = (short)f2bf(c0.w);
            fr[4] = (short)f2bf(c1.x); fr[5] = (short)f2bf(c1.y);
            fr[6] = (short)f2bf(c1.z); fr[7] = (short)f2bf(c1.w);
            afrag2[kc] = fr;
        }
    }
    #pragma unroll
    for (int np = 0; np < 8; np += 2) {
        f32x4 a0 = {0.f, 0.f, 0.f, 0.f};
        f32x4 a1 = {0.f, 0.f, 0.f, 0.f};
        const unsigned short* b0 = &Wsb[np * 16 + m16][quad * 8];
        const unsigned short* b1 = &Wsb[(np + 1) * 16 + m16][quad * 8];
        #pragma unroll
        for (int kc = 0; kc < 4; ++kc) {
            bf16x8 f0 = *(const bf16x8*)(b0 + kc * 32);
            bf16x8 f1 = *(const bf16x8*)(b1 + kc * 32);
            a0 = __builtin_amdgcn_mfma_f32_16x16x32_bf16(afrag2[kc], f0, a0, 0, 0, 0);
            a1 = __builtin_amdgcn_mfma_f32_16x16x32_bf16(afrag2[kc], f1, a1, 0, 0, 0);
        }
        accs[np] = a0; accs[np + 1] = a1;
    }
    __syncthreads();

    #pragma unroll
    for (int np = 0; np < 8; ++np) {
        int c = np * 16 + m16;
        float bb = biasb[c];
        #pragma unroll
        for (int r = 0; r < 4; ++r)
            Cs[wave * 16 + quad * 4 + r][c] = accs[np][r] + bb;
    }
    __syncthreads();

    const int s4 = t & 31;
    const int rb = t >> 5;
    float lsum[4] = {}, lsq[4] = {};
    #pragma unroll
    for (int i = 0; i < 8; ++i) {
        int r = rb + i * 8;
        int row = row0 + r;
        float4 v = *(const float4*)&Cs[r][s4 * 4];
        if (row < NNODES) {
            if (Cb) {
                ushort4 o;
                o.x = f2bf(v.x); o.y = f2bf(v.y);
                o.z = f2bf(v.z); o.w = f2bf(v.w);
                ((ushort4*)Cb)[(long)row * 32 + s4] = o;
            }
            if (Cf) ((float4*)Cf)[(long)row * 32 + s4] = v;
            lsum[0] += v.x; lsum[1] += v.y; lsum[2] += v.z; lsum[3] += v.w;
            lsq[0] = fmaf(v.x, v.x, lsq[0]);
            lsq[1] = fmaf(v.y, v.y, lsq[1]);
            lsq[2] = fmaf(v.z, v.z, lsq[2]);
            lsq[3] = fmaf(v.w, v.w, lsq[3]);
        }
    }
    #pragma unroll
    for (int j = 0; j < 4; ++j) {
        redp[(0 * 8 + rb) * 128 + s4 * 4 + j] = lsum[j];
        redp[(1 * 8 + rb) * 128 + s4 * 4 + j] = lsq[j];
    }
    __syncthreads();
    if (t < 128) {
        float s = 0.f, q = 0.f;
        #pragma unroll
        for (int g = 0; g < 8; ++g) {
            s += redp[g * 128 + t];
            q += redp[(8 + g) * 128 + t];
        }
        atomicAdd(&out_sum[t], s);
        atomicAdd(&out_sq[t],  q);
    }
}

// ================= BN fold =================
__global__ void bn_prep(const float* __restrict__ ssum, const float* __restrict__ ssq,
                        const float* __restrict__ gamma, const float* __restrict__ beta,
                        float* __restrict__ scale, float* __restrict__ shift)
{
    int c = threadIdx.x;
    const float invN = 1.0f / (float)NNODES;
    float m = ssum[c] * invN;
    float var = fmaf(-m, m, ssq[c] * invN);
    float rs = rsqrtf(var + 1e-5f);
    float sc = gamma[c] * rs;
    scale[c] = sc;
    shift[c] = beta[c] - m * sc;
}

// ========== projection + softmax, BN2+ReLU fused on load ==========
__global__ __launch_bounds__(256) void out_proj_softmax(
    const float* __restrict__ H, const float* __restrict__ Wout,
    const float* __restrict__ scale, const float* __restrict__ shift,
    const float* __restrict__ log_tau,
    float* __restrict__ outS, float* __restrict__ outL)
{
    __shared__ float As[HD][20];
    const int t = threadIdx.x;
    const long row0 = (long)blockIdx.x * 16;

    #pragma unroll
    for (int i = 0; i < 8; ++i) {
        int idx = t + i * 256;
        int r = idx >> 7, cc = idx & 127;
        float v = H[(row0 + r) * HD + cc];
        As[cc][r] = fmaxf(fmaf(v, scale[cc], shift[cc]), 0.f);
    }
    __syncthreads();

    const int c = t & 63;
    const int g = t >> 6;
    float acc[4] = {};

    float wq[8];
    #pragma unroll
    for (int i = 0; i < 8; ++i) wq[i] = Wout[i * KOUT + c];

    #pragma unroll 1
    for (int kc = 0; kc < HD; kc += 8) {
        float wn[8];
        if (kc + 8 < HD) {
            #pragma unroll
            for (int i = 0; i < 8; ++i) wn[i] = Wout[(kc + 8 + i) * KOUT + c];
        }
        #pragma unroll
        for (int i = 0; i < 8; ++i) {
            float4 a = *(const float4*)&As[kc + i][g * 4];
            acc[0] = fmaf(a.x, wq[i], acc[0]);
            acc[1] = fmaf(a.y, wq[i], acc[1]);
            acc[2] = fmaf(a.z, wq[i], acc[2]);
            acc[3] = fmaf(a.w, wq[i], acc[3]);
        }
        if (kc + 8 < HD) {
            #pragma unroll
            for (int i = 0; i < 8; ++i) wq[i] = wn[i];
        }
    }

    float inv_tau = __expf(-log_tau[0]);
    #pragma unroll
    for (int i = 0; i < 4; ++i) {
        float z = acc[i] * inv_tau;
        float m = z;
        #pragma unroll
        for (int o = 32; o > 0; o >>= 1) m = fmaxf(m, __shfl_xor(m, o));
        float e = __expf(z - m);
        float s = e;
        #pragma unroll
        for (int o = 32; o > 0; o >>= 1) s += __shfl_xor(s, o);
        long oi = (row0 + g * 4 + i) * KOUT + c;
        outS[oi] = e / s;
        outL[oi] = acc[i];
    }
}

extern "C" void kernel_launch(void* const* d_in, const int* in_sizes, int n_in,
                              void* d_out, int out_size, void* d_ws, size_t ws_size,
                              hipStream_t stream)
{
    const float* x      = (const float*)d_in[0];
    const int*   ei     = (const int*)d_in[1];
    const float* W1a    = (const float*)d_in[2];
    const float* b1a    = (const float*)d_in[3];
    const float* W1b    = (const float*)d_in[4];
    const float* b1b    = (const float*)d_in[5];
    const float* eps1   = (const float*)d_in[6];
    const float* gamma1 = (const float*)d_in[7];
    const float* beta1  = (const float*)d_in[8];
    const float* W2a    = (const float*)d_in[9];
    const float* b2a    = (const float*)d_in[10];
    const float* W2b    = (const float*)d_in[11];
    const float* b2b    = (const float*)d_in[12];
    const float* eps2   = (const float*)d_in[13];
    const float* gamma2 = (const float*)d_in[14];
    const float* beta2  = (const float*)d_in[15];
    const float* Wout   = (const float*)d_in[16];
    const float* ltau   = (const float*)d_in[17];

    const size_t NB = (size_t)NNODES * HD;
    float* B0 = (float*)d_ws;
    float* B1 = B0 + NB;
    float* B2 = B1 + NB;
    float* ST = B2 + NB;             // stats (1024 floats)
    float* sum1 = ST, *sq1 = ST + 128, *sum2 = ST + 256, *sq2 = ST + 384;
    float* scale1 = ST + 512, *shift1 = ST + 640, *scale2 = ST + 768, *shift2 = ST + 896;

    unsigned short* xb  = (unsigned short*)B2;   // bf16 x (CSR + gather1)
    unsigned short* h0b = (unsigned short*)B0;   // gather1 out; mlp1 in-place -> hb
    unsigned short* hb  = (unsigned short*)B0;   // h1 bf16
    unsigned short* h2b = (unsigned short*)B2;   // gather2 out

    int* I0        = (int*)(ST + 1024);
    int* deg       = I0;
    int* incl      = I0 + 50048;
    int* row_start = I0 + 2 * 50048;
    int* cur       = I0 + 3 * 50048;
    int* bsum      = I0 + 4 * 50048;
    int* bscan     = bsum + 256;
    int* col       = bscan + 256;               // NEDGES ints
    unsigned short* wt1a = (unsigned short*)(col + NEDGES);  // 4 x 128x128 bf16
    unsigned short* wt1b = wt1a + HD * HD;
    unsigned short* wt2a = wt1b + HD * HD;
    unsigned short* wt2b = wt2a + HD * HD;

    const int SCAN_BLKS = (NNODES + 255) / 256;   // 196
    const int GEMM_BLKS = (NNODES + 63) / 64;     // 782
    const int GATH_BLKS = (NNODES + 31) / 32;     // 1563

    hipMemsetAsync(ST, 0, 512 * sizeof(float), stream);
    hipMemsetAsync(deg, 0, NNODES * sizeof(int), stream);
    prep_all<<<6506 + 3125, 256, 0, stream>>>(x, xb, W1a, W1b, W2a, W2b,
                                              wt1a, wt1b, wt2a, wt2b, ei, deg);
    scan_a<<<SCAN_BLKS, 256, 0, stream>>>(deg, incl, bsum);
    scan_b<<<1, 256, 0, stream>>>(bsum, bscan, SCAN_BLKS);
    scan_c<<<SCAN_BLKS, 256, 0, stream>>>(deg, incl, bscan, row_start, cur);
    edge_fill<<<2048, 256, 0, stream>>>(ei, cur, col);

    // ---- layer 1
    gin_gather_w<false><<<GATH_BLKS, 256, 0, stream>>>(
        xb, col, row_start, cur, eps1, nullptr, nullptr, h0b);
    mlp_mfma<<<GEMM_BLKS, 256, 0, stream>>>(
        h0b, wt1a, b1a, wt1b, b1b, hb, nullptr, sum1, sq1);
    bn_prep<<<1, 128, 0, stream>>>(sum1, sq1, gamma1, beta1, scale1, shift1);

    // ---- layer 2 (BN1+ReLU fused into gather reads)
    gin_gather_w<true><<<GATH_BLKS, 256, 0, stream>>>(
        hb, col, row_start, cur, eps2, scale1, shift1, h2b);
    mlp_mfma<<<GEMM_BLKS, 256, 0, stream>>>(
        h2b, wt2a, b2a, wt2b, b2b, nullptr, B1, sum2, sq2);
    bn_prep<<<1, 128, 0, stream>>>(sum2, sq2, gamma2, beta2, scale2, shift2);

    // ---- projection + softmax (BN2+ReLU fused on load)
    out_proj_softmax<<<NNODES / 16, 256, 0, stream>>>(
        B1, Wout, scale2, shift2, ltau,
        (float*)d_out, (float*)d_out + (size_t)NNODES * KOUT);
}